// Round 1
// baseline (689.792 us; speedup 1.0000x reference)
//
#include <hip/hip_runtime.h>
#include <cstddef>

// Fused single-head causal attention for B=4096, T=96, C=256, H=64.
// out = softmax(mask((x@Wq)(x@Wk)^T * C^-0.5)) @ (x@Wv)
//
// Strategy: one block per batch element, 384 threads = 6 waves, each wave owns
// a 16-row tile of T. bf16 MFMA (16x16x32) for all three matmuls; x read once
// from HBM (dominant traffic, ~403 MB); weights pre-packed to MFMA B-fragment
// order in d_ws by a tiny kernel (L2-resident thereafter).

typedef __bf16 bf16x8 __attribute__((ext_vector_type(8)));
typedef float f32x4 __attribute__((ext_vector_type(4)));

static __device__ __forceinline__ unsigned short f2bf_u16(float f) {
  union { float f; unsigned int u; } c; c.f = f;
  // round-to-nearest-even fp32 -> bf16 (no NaN handling needed here)
  return (unsigned short)((c.u + 0x7FFFu + ((c.u >> 16) & 1u)) >> 16);
}

// ---------------- weight packing: fp32 [256][64] -> bf16 B-fragment order ----
// pack[p][kt][nt][lane][j] = bf16(W_p[32*kt + (lane>>4)*8 + j][16*nt + (lane&15)])
__global__ void pack_w(const float* __restrict__ Wk, const float* __restrict__ Wq,
                       const float* __restrict__ Wv, unsigned short* __restrict__ pack) {
  int idx = blockIdx.x * blockDim.x + threadIdx.x;  // (p,kt,nt,lane), 3*8*4*64 = 6144
  int lane = idx & 63;
  int t = idx >> 6;
  int nt = t & 3; t >>= 2;
  int kt = t & 7; t >>= 3;
  int p  = t;
  if (p >= 3) return;
  const float* W = (p == 0) ? Wk : (p == 1) ? Wq : Wv;
  int k0 = kt * 32 + (lane >> 4) * 8;
  int n  = nt * 16 + (lane & 15);
  unsigned short* dst = pack + (size_t)idx * 8;
#pragma unroll
  for (int j = 0; j < 8; ++j) dst[j] = f2bf_u16(W[(size_t)(k0 + j) * 64 + n]);
}

// ---------------- fused attention ----------------
#define LDQ 72    // 96x(64+8) bf16: row stride 144 B -> 2-way LDS bank alias (free)
#define LDV 104   // 64x(96+8) bf16: vT, row stride 208 B -> 2-way
#define LDP 104   // 96x(96+8) bf16: P

__global__ __launch_bounds__(384, 3) void head_fused(
    const float* __restrict__ x, const unsigned short* __restrict__ pack,
    float* __restrict__ out) {
  __shared__ __attribute__((aligned(16))) unsigned short qs [96 * LDQ];
  __shared__ __attribute__((aligned(16))) unsigned short ksm[96 * LDQ];
  __shared__ __attribute__((aligned(16))) unsigned short vTs[64 * LDV];
  __shared__ __attribute__((aligned(16))) unsigned short Ps [96 * LDP];
  __shared__ float rowsum[96];
  // total LDS = 13824+13824+13312+19968+384 = 61312 B -> 2 blocks/CU

  const int b    = blockIdx.x;
  const int w    = threadIdx.x >> 6;   // wave id, 0..5 -> owns rows 16w..16w+15
  const int lane = threadIdx.x & 63;
  const int lo   = lane & 15;          // MFMA col / A-row index
  const int hi   = lane >> 4;          // 0..3

  const float* __restrict__ xb = x + (size_t)b * (96 * 256);

  // ---- Phase 1: [q|k|v] = x @ [Wq|Wk|Wv], M=96 K=256 N=64 each ----
  f32x4 acc[3][4];
#pragma unroll
  for (int p = 0; p < 3; ++p)
#pragma unroll
    for (int nt = 0; nt < 4; ++nt) acc[p][nt] = (f32x4){0.f, 0.f, 0.f, 0.f};

  const int am = 16 * w + lo;  // x row this lane supplies for the A-fragment
#pragma unroll 2
  for (int kt = 0; kt < 8; ++kt) {
    const float* src = xb + (size_t)am * 256 + kt * 32 + hi * 8;
    f32x4 a0 = *(const f32x4*)src;
    f32x4 a1 = *(const f32x4*)(src + 4);
    union { bf16x8 v; unsigned short u[8]; } af;
#pragma unroll
    for (int j = 0; j < 4; ++j) { af.u[j] = f2bf_u16(a0[j]); af.u[4 + j] = f2bf_u16(a1[j]); }
#pragma unroll
    for (int p = 0; p < 3; ++p) {
#pragma unroll
      for (int nt = 0; nt < 4; ++nt) {
        bf16x8 bf = *(const bf16x8*)(pack + ((size_t)(((p * 8 + kt) * 4 + nt) * 64 + lane) * 8));
        acc[p][nt] = __builtin_amdgcn_mfma_f32_16x16x32_bf16(af.v, bf, acc[p][nt], 0, 0, 0);
      }
    }
  }
  // D layout: row = 16w + hi*4 + r, col = 16nt + lo   (input order: Wk, Wq, Wv)
#pragma unroll
  for (int nt = 0; nt < 4; ++nt) {
#pragma unroll
    for (int r = 0; r < 4; ++r) {
      int row = 16 * w + hi * 4 + r;
      int col = 16 * nt + lo;
      ksm[row * LDQ + col] = f2bf_u16(acc[0][nt][r]);
      qs [row * LDQ + col] = f2bf_u16(acc[1][nt][r]);
      vTs[col * LDV + row] = f2bf_u16(acc[2][nt][r]);   // store v transposed
    }
  }
  __syncthreads();

  // ---- Phase 2: S = q @ k^T * (1/16), causal mask, online row softmax ----
  f32x4 sacc[6];
#pragma unroll
  for (int jt = 0; jt < 6; ++jt) sacc[jt] = (f32x4){0.f, 0.f, 0.f, 0.f};

  bf16x8 qf0 = *(const bf16x8*)(qs + (16 * w + lo) * LDQ + hi * 8);
  bf16x8 qf1 = *(const bf16x8*)(qs + (16 * w + lo) * LDQ + 32 + hi * 8);
  for (int jt = 0; jt <= w; ++jt) {   // causal: only tiles jt <= w
    bf16x8 kf0 = *(const bf16x8*)(ksm + (16 * jt + lo) * LDQ + hi * 8);
    bf16x8 kf1 = *(const bf16x8*)(ksm + (16 * jt + lo) * LDQ + 32 + hi * 8);
    sacc[jt] = __builtin_amdgcn_mfma_f32_16x16x32_bf16(qf0, kf0, sacc[jt], 0, 0, 0);
    sacc[jt] = __builtin_amdgcn_mfma_f32_16x16x32_bf16(qf1, kf1, sacc[jt], 0, 0, 0);
  }

  // each lane holds, per r in 0..3: row = 16w + hi*4 + r, one col (16jt+lo) per jt
#pragma unroll
  for (int r = 0; r < 4; ++r) {
    int row = 16 * w + hi * 4 + r;
    float pr[6];
    float mx = -1e30f;
    for (int jt = 0; jt <= w; ++jt) {
      int col = 16 * jt + lo;
      float s = sacc[jt][r] * 0.0625f;           // * C^-0.5 = 1/16
      s = (col <= row) ? s : -1e30f;             // causal mask
      pr[jt] = s;
      mx = fmaxf(mx, s);
    }
#pragma unroll
    for (int off = 1; off < 16; off <<= 1) mx = fmaxf(mx, __shfl_xor(mx, off, 64));
    float sum = 0.f;
    for (int jt = 0; jt <= w; ++jt) {
      float p = __expf(pr[jt] - mx);             // masked entries -> exp(-1e30) = 0
      pr[jt] = p;
      sum += p;
    }
#pragma unroll
    for (int off = 1; off < 16; off <<= 1) sum += __shfl_xor(sum, off, 64);
#pragma unroll
    for (int jt = 0; jt < 6; ++jt) {
      float p = (jt <= w) ? pr[jt] : 0.f;
      Ps[row * LDP + 16 * jt + lo] = f2bf_u16(p);
    }
    if (lo == 0) rowsum[row] = sum;
  }
  __syncthreads();

  // ---- Phase 3: O = P @ v, then normalize by rowsum on store ----
  f32x4 oacc[4];
#pragma unroll
  for (int nt = 0; nt < 4; ++nt) oacc[nt] = (f32x4){0.f, 0.f, 0.f, 0.f};

  const int ksmax = (16 * w + 15) >> 5;  // causal: skip all-zero K-chunks
  for (int ks = 0; ks <= ksmax; ++ks) {
    bf16x8 pf = *(const bf16x8*)(Ps + (16 * w + lo) * LDP + ks * 32 + hi * 8);
#pragma unroll
    for (int nt = 0; nt < 4; ++nt) {
      bf16x8 vf = *(const bf16x8*)(vTs + (16 * nt + lo) * LDV + ks * 32 + hi * 8);
      oacc[nt] = __builtin_amdgcn_mfma_f32_16x16x32_bf16(pf, vf, oacc[nt], 0, 0, 0);
    }
  }

  float* __restrict__ ob = out + (size_t)b * (96 * 64);
#pragma unroll
  for (int r = 0; r < 4; ++r) {
    int row = 16 * w + hi * 4 + r;
    float inv = 1.0f / rowsum[row];
#pragma unroll
    for (int nt = 0; nt < 4; ++nt) {
      ob[row * 64 + 16 * nt + lo] = oacc[nt][r] * inv;
    }
  }
}

extern "C" void kernel_launch(void* const* d_in, const int* in_sizes, int n_in,
                              void* d_out, int out_size, void* d_ws, size_t ws_size,
                              hipStream_t stream) {
  const float* x  = (const float*)d_in[0];
  const float* Wk = (const float*)d_in[1];
  const float* Wq = (const float*)d_in[2];
  const float* Wv = (const float*)d_in[3];
  float* out = (float*)d_out;
  unsigned short* pack = (unsigned short*)d_ws;  // 3*8*4*64*8 u16 = 96 KB

  const int B = in_sizes[0] / (96 * 256);

  pack_w<<<24, 256, 0, stream>>>(Wk, Wq, Wv, pack);
  head_fused<<<B, 384, 0, stream>>>(x, pack, out);
}